// Round 5
// baseline (802.493 us; speedup 1.0000x reference)
//
#include <hip/hip_runtime.h>
#include <cstddef>
#include <cstdint>

#define NB   8
#define LQ   1024
#define CH   512
#define HHE  8
#define HDD  64
#define PPM  16
#define LP   1040     // L + P
#define HID  2048

typedef unsigned short ushort_t;
typedef __attribute__((ext_vector_type(8))) short short8;
typedef __attribute__((ext_vector_type(4))) float floatx4;

// ---- workspace layout (float element offsets) ----
static const size_t O_QB   = 0;          // Qb bf16   (2,097,152 fl)
static const size_t O_KB   = 2097152;    // Kb bf16   (2,129,920 fl)
static const size_t O_VB   = 4227072;    // Vb bf16   (2,129,920 fl)
static const size_t O_VT   = 6356992;    // VT bf16   (2,129,920 fl)
static const size_t O_AOB  = 8486912;    // aob bf16  (2,097,152 fl)
static const size_t O_AF   = 10584064;   // abf/fbf fp32 (4,194,304 fl)
// hraw bf16 overlays floats [0 .. 16,777,216) -- all of the above are dead then
static const size_t O_X1B  = 16777216;   // x1b padded bf16 (2,101,248 fl)
static const size_t O_HPAD = 18878464;   // hpad bf16 (8,404,992 fl)
static const size_t O_W1   = 27283456;   // w1 bf16   (3,145,728 fl)
static const size_t O_W2   = 30429184;   // w2 bf16   (1,572,864 fl)
static const size_t O_WO   = 32002048;   // wo bf16   (131,072 fl)
// total 32,133,120 floats = 128.5 MB

__device__ __forceinline__ ushort_t f2bf(float f) {
  uint32_t u = __float_as_uint(f);
  u += 0x7FFFu + ((u >> 16) & 1u);
  return (ushort_t)(u >> 16);
}
__device__ __forceinline__ float bf2f(ushort_t h) {
  return __uint_as_float(((uint32_t)h) << 16);
}

__device__ __forceinline__ void async16(ushort_t* lds, const ushort_t* g) {
  __builtin_amdgcn_global_load_lds(
      (const __attribute__((address_space(1))) void*)g,
      (__attribute__((address_space(3))) void*)lds, 16, 0, 0);
}

// ---------------------------------------------------------------------------
// weight pack to bf16 [oc][k], k = dl*IC + ic; src[oc*K + ic*KD + dl]
// ---------------------------------------------------------------------------
__global__ __launch_bounds__(256) void pack_bf16_kernel(
    const float* __restrict__ src, ushort_t* __restrict__ dst,
    int K, int KD, int icShift)
{
  const int oc = blockIdx.x;
  const int icMask = (1 << icShift) - 1;
  for (int k = threadIdx.x; k < K; k += 256) {
    int ic = k & icMask, dl = k >> icShift;
    dst[(size_t)oc * K + k] = f2bf(src[(size_t)oc * K + ic * KD + dl]);
  }
}

// ---------------------------------------------------------------------------
// Generic bf16 MFMA GEMM, 128x128 tile, BK=32, global_load_lds staging.
// ---------------------------------------------------------------------------
template<int EPI>
__global__ __launch_bounds__(256, 2) void mfma_gemm(
    const ushort_t* __restrict__ Ab, const ushort_t* __restrict__ Bb,
    int K, int BS, int P, int NOUT,
    const float* __restrict__ bias, const float* __restrict__ res,
    float* __restrict__ outf, ushort_t* __restrict__ outh)
{
  __shared__ ushort_t As[128 * 32];
  __shared__ ushort_t Bs[128 * 32];
  const int t = threadIdx.x;
  const int w = t >> 6, l = t & 63;
  const int m0 = blockIdx.x * 128, n0 = blockIdx.y * 128;

  const int sub = l >> 2;
  const int kc8 = (l & 3) * 8;
  const ushort_t* aptr[2];
  const ushort_t* bptr[2];
  #pragma unroll
  for (int c = 0; c < 2; ++c) {
    int arow = m0 + w * 32 + c * 16 + sub;
    aptr[c] = Ab + (size_t)(arow >> 10) * BS + (size_t)(arow & 1023) * P + kc8;
    int brow = n0 + w * 32 + c * 16 + sub;
    bptr[c] = Bb + (size_t)brow * K + kc8;
  }

  const int wm = w >> 1, wn = w & 1;
  const int lm = l & 15, q = l >> 4;
  floatx4 acc[4][4];
  #pragma unroll
  for (int i = 0; i < 4; ++i)
    #pragma unroll
    for (int j = 0; j < 4; ++j)
      acc[i][j] = (floatx4){0.f, 0.f, 0.f, 0.f};

  const int kIters = K >> 5;
  for (int kt = 0; kt < kIters; ++kt) {
    __syncthreads();
    async16(&As[w * 1024 +   0], aptr[0]);
    async16(&As[w * 1024 + 512], aptr[1]);
    async16(&Bs[w * 1024 +   0], bptr[0]);
    async16(&Bs[w * 1024 + 512], bptr[1]);
    aptr[0] += 32; aptr[1] += 32; bptr[0] += 32; bptr[1] += 32;
    __syncthreads();
    short8 af[4], bf[4];
    #pragma unroll
    for (int i = 0; i < 4; ++i)
      af[i] = *(const short8*)&As[(wm * 64 + i * 16 + lm) * 32 + q * 8];
    #pragma unroll
    for (int i = 0; i < 4; ++i)
      bf[i] = *(const short8*)&Bs[(wn * 64 + i * 16 + lm) * 32 + q * 8];
    #pragma unroll
    for (int i = 0; i < 4; ++i)
      #pragma unroll
      for (int j = 0; j < 4; ++j)
        acc[i][j] = __builtin_amdgcn_mfma_f32_16x16x32_bf16(af[i], bf[j], acc[i][j], 0, 0, 0);
  }

  #pragma unroll
  for (int i = 0; i < 4; ++i) {
    #pragma unroll
    for (int j = 0; j < 4; ++j) {
      const int mbase = m0 + wm * 64 + i * 16 + q * 4;
      const int n = n0 + wn * 64 + j * 16 + lm;
      #pragma unroll
      for (int r = 0; r < 4; ++r) {
        const int m = mbase + r;
        float v = acc[i][j][r];
        if (EPI == 0) {
          outh[(size_t)m * NOUT + n] = f2bf(v);
        } else if (EPI == 1) {
          outf[(size_t)m * NOUT + n] = v + bias[n];
        } else {
          outf[(size_t)m * NOUT + n] = v + bias[n] + res[(size_t)m * NOUT + n];
        }
      }
    }
  }
}

// ---------------------------------------------------------------------------
// QKV projection via MFMA. grid (128, 3)
// ---------------------------------------------------------------------------
__global__ __launch_bounds__(256) void qkv_mfma(
    const float* __restrict__ x,
    const float* __restrict__ Wq, const float* __restrict__ Wk, const float* __restrict__ Wv,
    ushort_t* __restrict__ qo, ushort_t* __restrict__ ko, ushort_t* __restrict__ vo)
{
  __shared__ ushort_t Ws[8 * 512];
  const int mat = blockIdx.y;
  const float* __restrict__ W = (mat == 0) ? Wq : (mat == 1) ? Wk : Wv;
  const int t = threadIdx.x;

  for (int e = t; e < 4096; e += 256) {
    const int oc = e >> 6, ic = e & 63;
    const int nt = oc >> 4, lmm = oc & 15, s = ic >> 5, qd = (ic >> 3) & 3, j = ic & 7;
    Ws[(((nt * 2 + s) * 4 + qd) * 16 + lmm) * 8 + j] = f2bf(W[e]);
  }

  const int w = t >> 6, l = t & 63;
  const int lm = l & 15, quad = l >> 4;
  const int tok0 = blockIdx.x * 64 + w * 16;

  short8 af[16];
  {
    const float* xrow = x + (size_t)(tok0 + lm) * CH + quad * 8;
    #pragma unroll
    for (int h = 0; h < 8; ++h) {
      #pragma unroll
      for (int s = 0; s < 2; ++s) {
        const float4 a = *(const float4*)(xrow + h * 64 + s * 32);
        const float4 b = *(const float4*)(xrow + h * 64 + s * 32 + 4);
        short8 f;
        f[0] = (short)f2bf(a.x); f[1] = (short)f2bf(a.y);
        f[2] = (short)f2bf(a.z); f[3] = (short)f2bf(a.w);
        f[4] = (short)f2bf(b.x); f[5] = (short)f2bf(b.y);
        f[6] = (short)f2bf(b.z); f[7] = (short)f2bf(b.w);
        af[h * 2 + s] = f;
      }
    }
  }
  __syncthreads();

  short8 bfr[8];
  #pragma unroll
  for (int nt = 0; nt < 4; ++nt)
    #pragma unroll
    for (int s = 0; s < 2; ++s)
      bfr[nt * 2 + s] = *(const short8*)&Ws[((nt * 2 + s) * 64 + l) * 8];

  const int n = tok0 >> 10, lpos = tok0 & 1023;
  ushort_t* outp;
  size_t base;
  if (mat == 0) { base = ((size_t)n * LQ + lpos) * CH; outp = qo; }
  else          { base = ((size_t)n * LP + lpos) * CH; outp = (mat == 1) ? ko : vo; }

  #pragma unroll
  for (int h = 0; h < 8; ++h) {
    floatx4 acc[4];
    #pragma unroll
    for (int nt = 0; nt < 4; ++nt) acc[nt] = (floatx4){0.f, 0.f, 0.f, 0.f};
    #pragma unroll
    for (int nt = 0; nt < 4; ++nt)
      #pragma unroll
      for (int s = 0; s < 2; ++s)
        acc[nt] = __builtin_amdgcn_mfma_f32_16x16x32_bf16(
            af[h * 2 + s], bfr[nt * 2 + s], acc[nt], 0, 0, 0);
    #pragma unroll
    for (int nt = 0; nt < 4; ++nt)
      #pragma unroll
      for (int r = 0; r < 4; ++r)
        outp[base + (size_t)(quad * 4 + r) * CH + h * 64 + nt * 16 + lm] =
            f2bf(acc[nt][r]);
  }
}

__global__ __launch_bounds__(256) void persist_kernel(
    const float* __restrict__ pk, const float* __restrict__ pv,
    ushort_t* __restrict__ ko, ushort_t* __restrict__ vo)
{
  const int t = blockIdx.x * 256 + threadIdx.x;
  const int n = t >> 13, p = (t >> 9) & 15, c = t & 511, d = c & 63;
  const size_t o = ((size_t)n * LP + LQ + p) * CH + c;
  ko[o] = f2bf(pk[p * 64 + d]);
  vo[o] = f2bf(pv[p * 64 + d]);
}

// ---------------------------------------------------------------------------
// V transpose: Vb [n][k(1040)][512] -> VT [n][d(512)][1040]
// ---------------------------------------------------------------------------
__global__ __launch_bounds__(256) void vtrans_kernel(
    const ushort_t* __restrict__ Vb, ushort_t* __restrict__ VT)
{
  __shared__ ushort_t Ls[16 * 520];
  const int n = blockIdx.y, k0 = blockIdx.x * 16;
  const int t = threadIdx.x;
  const int r = t >> 4;
  {
    const ushort_t* src = Vb + ((size_t)(n * LP + k0 + r)) * 512 + (t & 15) * 8;
    ushort_t* dst = &Ls[r * 520 + (t & 15) * 8];
    #pragma unroll
    for (int it = 0; it < 4; ++it)
      *(short8*)(dst + it * 128) = *(const short8*)(src + it * 128);
  }
  __syncthreads();
  #pragma unroll
  for (int rep = 0; rep < 2; ++rep) {
    const int d = t + rep * 256;
    short8 v0, v1;
    #pragma unroll
    for (int j = 0; j < 8; ++j) {
      v0[j] = (short)Ls[j * 520 + d];
      v1[j] = (short)Ls[(8 + j) * 520 + d];
    }
    ushort_t* dst = VT + ((size_t)(n * 512 + d)) * LP + k0;
    *(short8*)(dst)     = v0;
    *(short8*)(dst + 8) = v1;
  }
}

// ---------------------------------------------------------------------------
// MFMA flash attention v2.
// Pass 1 (z-stats): key-steps split across waves, K B-frags direct from
// global, static analytic max m-hat (exact softmax; m-hat cancels).
// Pass 2: gg-split, K/V^T staged via global_load_lds in FRAGMENT order
// (wave-contiguous ds_read_b128, conflict-free).
// ---------------------------------------------------------------------------
__global__ __launch_bounds__(256, 2) void attn_mfma(
    const ushort_t* __restrict__ Qb, const ushort_t* __restrict__ Kb,
    const ushort_t* __restrict__ VT,
    const float* __restrict__ thpre, const float* __restrict__ thpost,
    ushort_t* __restrict__ aob)
{
  __shared__ ushort_t Ks[16 * 512];   // 16 d-chunks, frag order (1 KB each)
  __shared__ ushort_t Vt[32 * 512];   // 32 d-chunks for 32-key pair
  __shared__ float    Ps[8 * 16 * 36];
  __shared__ float    zred[4 * 8 * 16];
  __shared__ float    zil[8 * 16];
  const int n = blockIdx.y, q0 = blockIdx.x * 16;
  const int t = threadIdx.x;
  const int w = t >> 6, l = t & 63;
  const int lm = l & 15, quad = l >> 4;
  const float invs = 0.044194173824159216f;  // 1/sqrt(512)
  const float GU = 8.0f;

  // persistent Q fragments: A[m=lm][k = c*32 + quad*8 + j]
  short8 qf[16];
  {
    const ushort_t* qrow = Qb + ((size_t)(n * LQ + q0 + lm)) * 512 + quad * 8;
    #pragma unroll
    for (int c = 0; c < 16; ++c) qf[c] = *(const short8*)(qrow + c * 32);
  }

  // talking-heads params (wave-uniform)
  float tps[8][8], psl[8];
  #pragma unroll
  for (int g = 0; g < 8; ++g) {
    float ps = 0.f;
    #pragma unroll
    for (int h = 0; h < 8; ++h) {
      float tv = thpre[g * 8 + h] * invs;
      tps[g][h] = tv;
      ps += tv * (1.0f / (float)(2 << h));   // slope_h = 2^-(h+1)
    }
    psl[g] = ps;
  }
  float tpo[2][8];
  #pragma unroll
  for (int gg = 0; gg < 2; ++gg)
    #pragma unroll
    for (int g = 0; g < 8; ++g) tpo[gg][g] = thpost[(w * 2 + gg) * 8 + g];

  // static max estimate (upper bound on s): rows quad*4..quad*4+3
  const int qlo = q0 + quad * 4;
  const float maxd = (float)max(qlo + 3, 1023 - qlo);
  float mh[8];
  #pragma unroll
  for (int g = 0; g < 8; ++g) mh[g] = GU + fmaxf(0.f, -psl[g] * maxd);

  // ---------------- pass 1: z (key-split, no LDS, no barriers) ----------
  float z_[8][4];
  #pragma unroll
  for (int g = 0; g < 8; ++g)
    #pragma unroll
    for (int r = 0; r < 4; ++r) z_[g][r] = 0.f;

  for (int step = w; step < 65; step += 4) {
    const int k0 = step * 16;
    const ushort_t* krow = Kb + ((size_t)(n * LP + k0 + lm)) * 512 + quad * 8;
    short8 kf[16];
    #pragma unroll
    for (int c = 0; c < 16; ++c) kf[c] = *(const short8*)(krow + c * 32);
    floatx4 ef[8];
    #pragma unroll
    for (int h = 0; h < 8; ++h) {
      floatx4 e = (floatx4){0.f, 0.f, 0.f, 0.f};
      e = __builtin_amdgcn_mfma_f32_16x16x32_bf16(qf[2 * h],     kf[2 * h],     e, 0, 0, 0);
      e = __builtin_amdgcn_mfma_f32_16x16x32_bf16(qf[2 * h + 1], kf[2 * h + 1], e, 0, 0, 0);
      ef[h] = e;
    }
    const bool alibi = (step < 64);
    #pragma unroll
    for (int r = 0; r < 4; ++r) {
      const float dist = fabsf((float)(q0 + quad * 4 + r - (k0 + lm)));
      #pragma unroll
      for (int g = 0; g < 8; ++g) {
        float s = tps[g][0] * ef[0][r];
        #pragma unroll
        for (int h = 1; h < 8; ++h) s += tps[g][h] * ef[h][r];
        if (alibi) s -= dist * psl[g];
        z_[g][r] += __expf(s - mh[g]);
      }
    }
  }
  // reduce over the 16 lm lanes of each quad group
  #pragma unroll
  for (int off = 1; off < 16; off <<= 1)
    #pragma unroll
    for (int g = 0; g < 8; ++g)
      #pragma unroll
      for (int r = 0; r < 4; ++r) z_[g][r] += __shfl_xor(z_[g][r], off);
  if (lm == 0) {
    #pragma unroll
    for (int g = 0; g < 8; ++g)
      #pragma unroll
      for (int r = 0; r < 4; ++r)
        zred[(w * 8 + g) * 16 + quad * 4 + r] = z_[g][r];
  }
  __syncthreads();
  if (t < 128) {
    const int g = t >> 4, qq = t & 15;
    float s = zred[g * 16 + qq] + zred[(8 + g) * 16 + qq] +
              zred[(16 + g) * 16 + qq] + zred[(24 + g) * 16 + qq];
    zil[g * 16 + qq] = 1.0f / s;
  }
  __syncthreads();
  float ziR[2][4];
  #pragma unroll
  for (int gg = 0; gg < 2; ++gg)
    #pragma unroll
    for (int r = 0; r < 4; ++r)
      ziR[gg][r] = zil[(w * 2 + gg) * 16 + quad * 4 + r];

  // ---------------- pass 2: P + AV ----------------
  floatx4 o_[2][4];
  #pragma unroll
  for (int gg = 0; gg < 2; ++gg)
    #pragma unroll
    for (int ch = 0; ch < 4; ++ch) o_[gg][ch] = (floatx4){0.f, 0.f, 0.f, 0.f};

  for (int pair = 0; pair < 33; ++pair) {
    const int k0p = pair * 32;
    const int nsub = (pair == 32) ? 1 : 2;
    __syncthreads();   // previous pair's Vt/Ks fully consumed
    // stage V^T chunks (frag order): chunk dc: B[n=dc*16+lm][k=k0p+quad*8+j]
    #pragma unroll
    for (int i = 0; i < 8; ++i) {
      const int dc = w * 8 + i;
      async16(&Vt[dc * 512],
              VT + ((size_t)(n * 512 + dc * 16 + lm)) * LP + k0p + quad * 8);
    }
    // stage K chunks for sub 0
    #pragma unroll
    for (int i = 0; i < 4; ++i) {
      const int c = w * 4 + i;
      async16(&Ks[c * 512],
              Kb + ((size_t)(n * LP + k0p + lm)) * 512 + c * 32 + quad * 8);
    }
    __syncthreads();
    for (int sub = 0; sub < nsub; ++sub) {
      const int step = pair * 2 + sub, k0 = k0p + sub * 16;
      floatx4 ef[8];
      #pragma unroll
      for (int h = 0; h < 8; ++h) {
        floatx4 e = (floatx4){0.f, 0.f, 0.f, 0.f};
        e = __builtin_amdgcn_mfma_f32_16x16x32_bf16(
            qf[2 * h], *(const short8*)&Ks[(2 * h) * 512 + l * 8], e, 0, 0, 0);
        e = __builtin_amdgcn_mfma_f32_16x16x32_bf16(
            qf[2 * h + 1], *(const short8*)&Ks[(2 * h + 1) * 512 + l * 8], e, 0, 0, 0);
        ef[h] = e;
      }
      const bool alibi = (step < 64);
      #pragma unroll
      for (int r = 0; r < 4; ++r) {
        const float dist = fabsf((float)(q0 + quad * 4 + r - (k0 + lm)));
        #pragma unroll
        for (int gg = 0; gg < 2; ++gg) {
          const int g = w * 2 + gg;
          float s = tps[g][0] * ef[0][r];
          #pragma unroll
          for (int h = 1; h < 8; ++h) s += tps[g][h] * ef[h][r];
          if (alibi) s -= dist * psl[g];
          const float p = __expf(s - mh[g]) * ziR[gg][r];
          Ps[(g * 16 + quad * 4 + r) * 36 + sub * 16 + lm] = p;
          if (pair == 32)
            Ps[(g * 16 + quad * 4 + r) * 36 + 16 + lm] = 0.f;
        }
      }
      if (sub == 0 && nsub == 2) {
        __syncthreads();   // Ks sub-0 consumed by all waves
        #pragma unroll
        for (int i = 0; i < 4; ++i) {
          const int c = w * 4 + i;
          async16(&Ks[c * 512],
                  Kb + ((size_t)(n * LP + k0p + 16 + lm)) * 512 + c * 32 + quad * 8);
        }
        __syncthreads();
      }
    }
    __syncthreads();   // Ps complete
    // tpost mix + AV
    float pm[2][8];
    #pragma unroll
    for (int gg = 0; gg < 2; ++gg)
      #pragma unroll
      for (int j = 0; j < 8; ++j) pm[gg][j] = 0.f;
    #pragma unroll
    for (int g = 0; g < 8; ++g) {
      const float4 pa = *(const float4*)&Ps[(g * 16 + lm) * 36 + quad * 8];
      const float4 pb = *(const float4*)&Ps[(g * 16 + lm) * 36 + quad * 8 + 4];
      #pragma unroll
      for (int gg = 0; gg < 2; ++gg) {
        const float tw = tpo[gg][g];
        pm[gg][0] += tw * pa.x; pm[gg][1] += tw * pa.y;
        pm[gg][2] += tw * pa.z; pm[gg][3] += tw * pa.w;
        pm[gg][4] += tw * pb.x; pm[gg][5] += tw * pb.y;
        pm[gg][6] += tw * pb.z; pm[gg][7] += tw * pb.w;
      }
    }
    short8 pk[2];
    #pragma unroll
    for (int gg = 0; gg < 2; ++gg)
      #pragma unroll
      for (int j = 0; j < 8; ++j) pk[gg][j] = (short)f2bf(pm[gg][j]);
    #pragma unroll
    for (int gg = 0; gg < 2; ++gg)
      #pragma unroll
      for (int ch = 0; ch < 4; ++ch) {
        const int dc = (w * 2 + gg) * 4 + ch;
        o_[gg][ch] = __builtin_amdgcn_mfma_f32_16x16x32_bf16(
            pk[gg], *(const short8*)&Vt[dc * 512 + l * 8], o_[gg][ch], 0, 0, 0);
      }
  }

  #pragma unroll
  for (int gg = 0; gg < 2; ++gg)
    #pragma unroll
    for (int ch = 0; ch < 4; ++ch) {
      const int d = (w * 2 + gg) * 64 + ch * 16 + lm;
      #pragma unroll
      for (int r = 0; r < 4; ++r)
        aob[((size_t)(n * LQ + q0 + quad * 4 + r)) * 512 + d] = f2bf(o_[gg][ch][r]);
    }
}

// ---------------------------------------------------------------------------
// swiglu: h = silu(h1+b1)*(h2+b2), raw [8192][4096] bf16 -> padded bf16
// ---------------------------------------------------------------------------
__global__ __launch_bounds__(256) void swiglu_kernel(
    const ushort_t* __restrict__ hraw, const float* __restrict__ bias,
    ushort_t* __restrict__ hpad)
{
  const int tok = blockIdx.x;
  const int n = tok >> 10, l = tok & 1023;
  const size_t src = (size_t)tok * 4096;
  const size_t dst = ((size_t)n * 1026 + l + 1) * 2048;
  for (int c = threadIdx.x; c < 2048; c += 256) {
    float h1 = bf2f(hraw[src + c]) + bias[c];
    float h2 = bf2f(hraw[src + 2048 + c]) + bias[2048 + c];
    float s = h1 / (1.f + __expf(-h1));
    hpad[dst + c] = f2bf(s * h2);
  }
}

__global__ __launch_bounds__(256) void zero_pads_kernel(
    ushort_t* __restrict__ x1b, ushort_t* __restrict__ hpad)
{
  const int b = blockIdx.x;
  const int n = b >> 1, side = b & 1;
  const size_t r = (size_t)n * 1026 + side * 1025;
  ushort2 z; z.x = 0; z.y = 0;
  *(ushort2*)&x1b[r * 512 + threadIdx.x * 2] = z;
  #pragma unroll
  for (int i = 0; i < 4; ++i)
    *(ushort2*)&hpad[r * 2048 + (threadIdx.x + 256 * i) * 2] = z;
}

// ---------------------------------------------------------------------------
// LayerNorm (fp32) + optional bf16 padded copy
// ---------------------------------------------------------------------------
__global__ __launch_bounds__(256) void ln_kernel(
    const float* __restrict__ in, const float* __restrict__ res,
    const float* __restrict__ g, const float* __restrict__ b,
    float* __restrict__ outp, ushort_t* __restrict__ bfout)
{
  const int w = threadIdx.x >> 6, lane = threadIdx.x & 63;
  const int tok = blockIdx.x * 4 + w;
  const size_t base = (size_t)tok * CH;
  float4 v0 = *(const float4*)&in[base + (lane << 2)];
  float4 v1 = *(const float4*)&in[base + 256 + (lane << 2)];
  if (res != nullptr) {
    float4 r0 = *(const float4*)&res[base + (lane << 2)];
    float4 r1 = *(const float4*)&res[base + 256 + (lane << 2)];
    v0.x += r0.x; v0.y += r0.y; v0.z += r0.z; v0.w += r0.w;
    v1.x += r1.x; v1.y += r1.y; v1.z += r1.z; v1.w += r1.w;
  }
  float s = v0.x + v0.y + v0.z + v0.w + v1.x + v1.y + v1.z + v1.w;
  #pragma unroll
  for (int off = 32; off > 0; off >>= 1) s += __shfl_xor(s, off);
  const float mu = s * (1.f / 512.f);
  float d0 = v0.x - mu, d1 = v0.y - mu, d2 = v0.z - mu, d3 = v0.w - mu;
  float d4 = v1.x - mu, d5 = v1.y - mu, d6 = v1.z - mu, d7 = v1.w - mu;
  float vs = d0*d0 + d1*d1 + d2*d2 + d3*d3 + d4*d4 + d5*d5 + d6*d6 + d7*d7;
  #pragma unroll
  for (int off = 32; off > 0; off >>= 1) vs += __shfl_xor(vs, off);
  const float r = rsqrtf(vs * (1.f / 512.f) + 1e-5f);
  float4 ga = *(const float4*)&g[(lane << 2)];
  float4 gb = *(const float4*)&g[256 + (lane << 2)];
  float4 ba = *(const float4*)&b[(lane << 2)];
  float4 bb = *(const float4*)&b[256 + (lane << 2)];
  float4 o0, o1;
  o0.x = d0 * r * ga.x + ba.x; o0.y = d1 * r * ga.y + ba.y;
  o0.z = d2 * r * ga.z + ba.z; o0.w = d3 * r * ga.w + ba.w;
  o1.x = d4 * r * gb.x + bb.x; o1.y = d5 * r * gb.y + bb.y;
  o1.z = d6 * r * gb.z + bb.z; o1.w = d7 * r * gb.w + bb.w;
  *(float4*)&outp[base + (lane << 2)] = o0;
  *(float4*)&outp[base + 256 + (lane << 2)] = o1;
  if (bfout != nullptr) {
    const int n = tok >> 10, ll = tok & 1023;
    const size_t bb2 = ((size_t)n * 1026 + ll + 1) * 512;
    ushort4 u0 = make_ushort4(f2bf(o0.x), f2bf(o0.y), f2bf(o0.z), f2bf(o0.w));
    ushort4 u1 = make_ushort4(f2bf(o1.x), f2bf(o1.y), f2bf(o1.z), f2bf(o1.w));
    *(ushort4*)&bfout[bb2 + (lane << 2)] = u0;
    *(ushort4*)&bfout[bb2 + 256 + (lane << 2)] = u1;
  }
}

// ---------------------------------------------------------------------------
extern "C" void kernel_launch(void* const* d_in, const int* in_sizes, int n_in,
                              void* d_out, int out_size, void* d_ws, size_t ws_size,
                              hipStream_t stream)
{
  (void)in_sizes; (void)n_in; (void)out_size; (void)ws_size;
  const float* x      = (const float*)d_in[0];
  const float* Wq     = (const float*)d_in[1];
  const float* Wk     = (const float*)d_in[2];
  const float* Wv     = (const float*)d_in[3];
  const float* Wo     = (const float*)d_in[4];
  const float* bo     = (const float*)d_in[5];
  const float* th_pre = (const float*)d_in[6];
  const float* th_post= (const float*)d_in[7];
  const float* p_keys = (const float*)d_in[8];
  const float* p_vals = (const float*)d_in[9];
  const float* c1w    = (const float*)d_in[10];
  const float* c1b    = (const float*)d_in[11];
  const float* c2w    = (const float*)d_in[12];
  const float* c2b    = (const float*)d_in[13];
  const float* ln1g   = (const float*)d_in[14];
  const float* ln1b   = (const float*)d_in[15];
  const float* ln2g   = (const float*)d_in[16];
  const float* ln2b   = (const float*)d_in[17];

  float* ws  = (float*)d_ws;
  float* out = (float*)d_out;

  ushort_t* Qb   = (ushort_t*)(ws + O_QB);
  ushort_t* Kb   = (ushort_t*)(ws + O_KB);
  ushort_t* Vb   = (ushort_t*)(ws + O_VB);
  ushort_t* VT   = (ushort_t*)(ws + O_VT);
  ushort_t* aob  = (ushort_t*)(ws + O_AOB);
  float*    abf  = ws + O_AF;
  float*    fbf  = abf;
  ushort_t* x1b  = (ushort_t*)(ws + O_X1B);
  ushort_t* hpad = (ushort_t*)(ws + O_HPAD);
  ushort_t* hraw = (ushort_t*)ws;
  ushort_t* w1p  = (ushort_t*)(ws + O_W1);
  ushort_t* w2p  = (ushort_t*)(ws + O_W2);
  ushort_t* wop  = (ushort_t*)(ws + O_WO);

  pack_bf16_kernel<<<4096, 256, 0, stream>>>(c1w, w1p, 1536, 3, 9);
  pack_bf16_kernel<<<512,  256, 0, stream>>>(c2w, w2p, 6144, 3, 11);
  pack_bf16_kernel<<<512,  256, 0, stream>>>(Wo,  wop, 512,  1, 9);

  qkv_mfma<<<dim3(128, 3), 256, 0, stream>>>(x, Wq, Wk, Wv, Qb, Kb, Vb);
  persist_kernel<<<256, 256, 0, stream>>>(p_keys, p_vals, Kb, Vb);
  vtrans_kernel<<<dim3(65, 8), 256, 0, stream>>>(Vb, VT);

  attn_mfma<<<dim3(64, 8), 256, 0, stream>>>(Qb, Kb, VT, th_pre, th_post, aob);

  // Wo: M=8192 N=512 K=512, +bias +residual(x) -> abf fp32
  mfma_gemm<2><<<dim3(64, 4), 256, 0, stream>>>(
      aob, wop, 512, 1024 * 512, 512, 512, bo, x, abf, nullptr);

  ln_kernel<<<2048, 256, 0, stream>>>(abf, nullptr, ln1g, ln1b, out, x1b);
  zero_pads_kernel<<<16, 256, 0, stream>>>(x1b, hpad);

  // conv1: M=8192 N=4096 K=1536 -> hraw bf16
  mfma_gemm<0><<<dim3(64, 32), 256, 0, stream>>>(
      x1b, w1p, 1536, 1026 * 512, 512, 4096, nullptr, nullptr, nullptr, hraw);

  swiglu_kernel<<<8192, 256, 0, stream>>>(hraw, c1b, hpad);

  // conv2: M=8192 N=512 K=6144, +bias -> fbf fp32
  mfma_gemm<1><<<dim3(64, 4), 256, 0, stream>>>(
      hpad, w2p, 6144, 1026 * 2048, 2048, 512, c2b, nullptr, fbf, nullptr);

  ln_kernel<<<2048, 256, 0, stream>>>(fbf, out, ln2g, ln2b, out, nullptr);
}

// Round 6
// 728.290 us; speedup vs baseline: 1.1019x; 1.1019x over previous
//
#include <hip/hip_runtime.h>
#include <cstddef>
#include <cstdint>

#define NB   8
#define LQ   1024
#define CH   512
#define HHE  8
#define HDD  64
#define PPM  16
#define LP   1040     // L + P
#define HID  2048

typedef unsigned short ushort_t;
typedef __attribute__((ext_vector_type(8))) short short8;
typedef __attribute__((ext_vector_type(4))) float floatx4;

// ---- workspace layout (float element offsets) ----
static const size_t O_QB   = 0;          // Qb bf16   (2,097,152 fl)
static const size_t O_KB   = 2097152;    // Kb bf16 token-major (2,129,920 fl)
static const size_t O_VB   = 4227072;    // Vb bf16 token-major (2,129,920 fl)
static const size_t O_KF   = 6356992;    // Kf bf16 frag-order  (2,129,920 fl)
static const size_t O_VF   = 8486912;    // Vf bf16 frag-order  (2,228,224 fl)
static const size_t O_AOB  = 10715136;   // aob bf16  (2,097,152 fl)
static const size_t O_AF   = 12812288;   // abf/fbf fp32 (4,194,304 fl) -> ends 17,006,592
// hraw bf16 overlays floats [0 .. 16,777,216): all attn buffers + most of AF.
// Timeline-safe: abf read by ln1 before conv1 writes hraw; fbf written by conv2
// after swiglu consumed hraw.
static const size_t O_X1B  = 17006592;   // x1b padded bf16 (2,101,248 fl)
static const size_t O_HPAD = 19107840;   // hpad bf16 (8,404,992 fl)
static const size_t O_W1   = 27512832;   // w1 bf16   (3,145,728 fl)
static const size_t O_W2   = 30658560;   // w2 bf16   (1,572,864 fl)
static const size_t O_WO   = 32231424;   // wo bf16   (131,072 fl)
// total 32,362,496 floats = 129.4 MB

__device__ __forceinline__ ushort_t f2bf(float f) {
  uint32_t u = __float_as_uint(f);
  u += 0x7FFFu + ((u >> 16) & 1u);
  return (ushort_t)(u >> 16);
}
__device__ __forceinline__ float bf2f(ushort_t h) {
  return __uint_as_float(((uint32_t)h) << 16);
}

__device__ __forceinline__ void async16(ushort_t* lds, const ushort_t* g) {
  __builtin_amdgcn_global_load_lds(
      (const __attribute__((address_space(1))) void*)g,
      (__attribute__((address_space(3))) void*)lds, 16, 0, 0);
}

// ---------------------------------------------------------------------------
// weight pack to bf16 [oc][k], k = dl*IC + ic; src[oc*K + ic*KD + dl]
// ---------------------------------------------------------------------------
__global__ __launch_bounds__(256) void pack_bf16_kernel(
    const float* __restrict__ src, ushort_t* __restrict__ dst,
    int K, int KD, int icShift)
{
  const int oc = blockIdx.x;
  const int icMask = (1 << icShift) - 1;
  for (int k = threadIdx.x; k < K; k += 256) {
    int ic = k & icMask, dl = k >> icShift;
    dst[(size_t)oc * K + k] = f2bf(src[(size_t)oc * K + ic * KD + dl]);
  }
}

// ---------------------------------------------------------------------------
// Generic bf16 MFMA GEMM, 128x128 tile, BK=32, global_load_lds staging.
// ---------------------------------------------------------------------------
template<int EPI>
__global__ __launch_bounds__(256, 2) void mfma_gemm(
    const ushort_t* __restrict__ Ab, const ushort_t* __restrict__ Bb,
    int K, int BS, int P, int NOUT,
    const float* __restrict__ bias, const float* __restrict__ res,
    float* __restrict__ outf, ushort_t* __restrict__ outh)
{
  __shared__ ushort_t As[128 * 32];
  __shared__ ushort_t Bs[128 * 32];
  const int t = threadIdx.x;
  const int w = t >> 6, l = t & 63;
  const int m0 = blockIdx.x * 128, n0 = blockIdx.y * 128;

  const int sub = l >> 2;
  const int kc8 = (l & 3) * 8;
  const ushort_t* aptr[2];
  const ushort_t* bptr[2];
  #pragma unroll
  for (int c = 0; c < 2; ++c) {
    int arow = m0 + w * 32 + c * 16 + sub;
    aptr[c] = Ab + (size_t)(arow >> 10) * BS + (size_t)(arow & 1023) * P + kc8;
    int brow = n0 + w * 32 + c * 16 + sub;
    bptr[c] = Bb + (size_t)brow * K + kc8;
  }

  const int wm = w >> 1, wn = w & 1;
  const int lm = l & 15, q = l >> 4;
  floatx4 acc[4][4];
  #pragma unroll
  for (int i = 0; i < 4; ++i)
    #pragma unroll
    for (int j = 0; j < 4; ++j)
      acc[i][j] = (floatx4){0.f, 0.f, 0.f, 0.f};

  const int kIters = K >> 5;
  for (int kt = 0; kt < kIters; ++kt) {
    __syncthreads();
    async16(&As[w * 1024 +   0], aptr[0]);
    async16(&As[w * 1024 + 512], aptr[1]);
    async16(&Bs[w * 1024 +   0], bptr[0]);
    async16(&Bs[w * 1024 + 512], bptr[1]);
    aptr[0] += 32; aptr[1] += 32; bptr[0] += 32; bptr[1] += 32;
    __syncthreads();
    short8 af[4], bf[4];
    #pragma unroll
    for (int i = 0; i < 4; ++i)
      af[i] = *(const short8*)&As[(wm * 64 + i * 16 + lm) * 32 + q * 8];
    #pragma unroll
    for (int i = 0; i < 4; ++i)
      bf[i] = *(const short8*)&Bs[(wn * 64 + i * 16 + lm) * 32 + q * 8];
    #pragma unroll
    for (int i = 0; i < 4; ++i)
      #pragma unroll
      for (int j = 0; j < 4; ++j)
        acc[i][j] = __builtin_amdgcn_mfma_f32_16x16x32_bf16(af[i], bf[j], acc[i][j], 0, 0, 0);
  }

  #pragma unroll
  for (int i = 0; i < 4; ++i) {
    #pragma unroll
    for (int j = 0; j < 4; ++j) {
      const int mbase = m0 + wm * 64 + i * 16 + q * 4;
      const int n = n0 + wn * 64 + j * 16 + lm;
      #pragma unroll
      for (int r = 0; r < 4; ++r) {
        const int m = mbase + r;
        float v = acc[i][j][r];
        if (EPI == 0) {
          outh[(size_t)m * NOUT + n] = f2bf(v);
        } else if (EPI == 1) {
          outf[(size_t)m * NOUT + n] = v + bias[n];
        } else {
          outf[(size_t)m * NOUT + n] = v + bias[n] + res[(size_t)m * NOUT + n];
        }
      }
    }
  }
}

// ---------------------------------------------------------------------------
// QKV projection via MFMA. grid (128, 3)
// ---------------------------------------------------------------------------
__global__ __launch_bounds__(256) void qkv_mfma(
    const float* __restrict__ x,
    const float* __restrict__ Wq, const float* __restrict__ Wk, const float* __restrict__ Wv,
    ushort_t* __restrict__ qo, ushort_t* __restrict__ ko, ushort_t* __restrict__ vo)
{
  __shared__ ushort_t Ws[8 * 512];
  const int mat = blockIdx.y;
  const float* __restrict__ W = (mat == 0) ? Wq : (mat == 1) ? Wk : Wv;
  const int t = threadIdx.x;

  for (int e = t; e < 4096; e += 256) {
    const int oc = e >> 6, ic = e & 63;
    const int nt = oc >> 4, lmm = oc & 15, s = ic >> 5, qd = (ic >> 3) & 3, j = ic & 7;
    Ws[(((nt * 2 + s) * 4 + qd) * 16 + lmm) * 8 + j] = f2bf(W[e]);
  }

  const int w = t >> 6, l = t & 63;
  const int lm = l & 15, quad = l >> 4;
  const int tok0 = blockIdx.x * 64 + w * 16;

  short8 af[16];
  {
    const float* xrow = x + (size_t)(tok0 + lm) * CH + quad * 8;
    #pragma unroll
    for (int h = 0; h < 8; ++h) {
      #pragma unroll
      for (int s = 0; s < 2; ++s) {
        const float4 a = *(const float4*)(xrow + h * 64 + s * 32);
        const float4 b = *(const float4*)(xrow + h * 64 + s * 32 + 4);
        short8 f;
        f[0] = (short)f2bf(a.x); f[1] = (short)f2bf(a.y);
        f[2] = (short)f2bf(a.z); f[3] = (short)f2bf(a.w);
        f[4] = (short)f2bf(b.x); f[5] = (short)f2bf(b.y);
        f[6] = (short)f2bf(b.z); f[7] = (short)f2bf(b.w);
        af[h * 2 + s] = f;
      }
    }
  }
  __syncthreads();

  short8 bfr[8];
  #pragma unroll
  for (int nt = 0; nt < 4; ++nt)
    #pragma unroll
    for (int s = 0; s < 2; ++s)
      bfr[nt * 2 + s] = *(const short8*)&Ws[((nt * 2 + s) * 64 + l) * 8];

  const int n = tok0 >> 10, lpos = tok0 & 1023;
  ushort_t* outp;
  size_t base;
  if (mat == 0) { base = ((size_t)n * LQ + lpos) * CH; outp = qo; }
  else          { base = ((size_t)n * LP + lpos) * CH; outp = (mat == 1) ? ko : vo; }

  #pragma unroll
  for (int h = 0; h < 8; ++h) {
    floatx4 acc[4];
    #pragma unroll
    for (int nt = 0; nt < 4; ++nt) acc[nt] = (floatx4){0.f, 0.f, 0.f, 0.f};
    #pragma unroll
    for (int nt = 0; nt < 4; ++nt)
      #pragma unroll
      for (int s = 0; s < 2; ++s)
        acc[nt] = __builtin_amdgcn_mfma_f32_16x16x32_bf16(
            af[h * 2 + s], bfr[nt * 2 + s], acc[nt], 0, 0, 0);
    #pragma unroll
    for (int nt = 0; nt < 4; ++nt)
      #pragma unroll
      for (int r = 0; r < 4; ++r)
        outp[base + (size_t)(quad * 4 + r) * CH + h * 64 + nt * 16 + lm] =
            f2bf(acc[nt][r]);
  }
}

__global__ __launch_bounds__(256) void persist_kernel(
    const float* __restrict__ pk, const float* __restrict__ pv,
    ushort_t* __restrict__ ko, ushort_t* __restrict__ vo)
{
  const int t = blockIdx.x * 256 + threadIdx.x;
  const int n = t >> 13, p = (t >> 9) & 15, c = t & 511, d = c & 63;
  const size_t o = ((size_t)n * LP + LQ + p) * CH + c;
  ko[o] = f2bf(pk[p * 64 + d]);
  vo[o] = f2bf(pv[p * 64 + d]);
}

// ---------------------------------------------------------------------------
// K repack to fragment-order: Kf[((n*65+s)*16+c)*512 + lane*8 + j]
//   = K[n][key=s*16+lm][ch=c*32+quad*8+j],  lane = quad*16+lm
// grid (65, 8)
// ---------------------------------------------------------------------------
__global__ __launch_bounds__(256) void kfrag_kernel(
    const ushort_t* __restrict__ Kb, ushort_t* __restrict__ Kf)
{
  __shared__ ushort_t Ls[16 * 520];
  const int n = blockIdx.y, s = blockIdx.x;
  const int t = threadIdx.x;
  #pragma unroll
  for (int it = 0; it < 4; ++it) {
    int cid = t + 256 * it;
    int row = cid >> 6, cc = cid & 63;
    *(short8*)&Ls[row * 520 + cc * 8] =
        *(const short8*)&Kb[((size_t)(n * LP + s * 16 + row)) * 512 + cc * 8];
  }
  __syncthreads();
  const int lane = t & 63, quad = lane >> 4, lm = lane & 15;
  #pragma unroll
  for (int it = 0; it < 4; ++it) {
    int c = (t >> 6) + 4 * it;
    short8 v = *(const short8*)&Ls[lm * 520 + c * 32 + quad * 8];
    *(short8*)&Kf[((size_t)(n * 65 + s) * 16 + c) * 512 + lane * 8] = v;
  }
}

// ---------------------------------------------------------------------------
// V repack to AV-fragment-order:
// Vf[(((n*17+ss)*32+dc)*2+c32)*512 + lane*8 + j]
//   = V[n][key=ss*64+c32*32+quad*8+j][d=dc*16+lm], 0 beyond key 1039.
// grid (34, 8), blockIdx.x = ss*2 + c32
// ---------------------------------------------------------------------------
__global__ __launch_bounds__(256) void vfrag_kernel(
    const ushort_t* __restrict__ Vb, ushort_t* __restrict__ Vf)
{
  __shared__ ushort_t Ls[32 * 520];
  const int n = blockIdx.y, bx = blockIdx.x;
  const int k0 = bx * 32;
  const int t = threadIdx.x;
  #pragma unroll
  for (int it = 0; it < 8; ++it) {
    int cid = t + 256 * it;
    int row = cid >> 6, cc = cid & 63;
    short8 v = {};
    if (k0 + row < LP)
      v = *(const short8*)&Vb[((size_t)(n * LP + k0 + row)) * 512 + cc * 8];
    *(short8*)&Ls[row * 520 + cc * 8] = v;
  }
  __syncthreads();
  const int lane = t & 63, quad = lane >> 4, lm = lane & 15;
  const int ss = bx >> 1, c32 = bx & 1;
  #pragma unroll
  for (int it = 0; it < 8; ++it) {
    int dc = (t >> 6) + 4 * it;
    short8 v;
    #pragma unroll
    for (int j = 0; j < 8; ++j)
      v[j] = (short)Ls[(quad * 8 + j) * 520 + dc * 16 + lm];
    *(short8*)&Vf[(((size_t)(n * 17 + ss) * 32 + dc) * 2 + c32) * 512 + lane * 8] = v;
  }
}

// ---------------------------------------------------------------------------
// MFMA flash attention v4 — key-split both passes, frag-ordered global K/V
// (lane-contiguous loads, no K/V LDS, no staging barriers). Static m-hat
// exact softmax; tpost*zi folded into AV A-frag mix. 2 barriers / 64 keys.
// ---------------------------------------------------------------------------
__global__ __launch_bounds__(256, 2) void attn_v4(
    const ushort_t* __restrict__ Qb, const ushort_t* __restrict__ Kf,
    const ushort_t* __restrict__ Vf,
    const float* __restrict__ thpre, const float* __restrict__ thpost,
    ushort_t* __restrict__ aob)
{
  __shared__ float Ps[8 * 16 * 68];   // P~ [g][q][64k + pad4], fp32
  __shared__ float zred[4 * 8 * 16];
  __shared__ float zil[8 * 16];
  const int n = blockIdx.y, q0 = blockIdx.x * 16;
  const int t = threadIdx.x, w = t >> 6, l = t & 63;
  const int lm = l & 15, quad = l >> 4;
  const float invs = 0.044194173824159216f;  // 1/sqrt(512)

  // persistent Q A-fragments: A[m=lm][k=c*32+quad*8+j]
  short8 qf[16];
  {
    const ushort_t* qrow = Qb + ((size_t)(n * LQ + q0 + lm)) * 512 + quad * 8;
    #pragma unroll
    for (int c = 0; c < 16; ++c) qf[c] = *(const short8*)(qrow + c * 32);
  }

  // pre-softmax talking heads (all 8 g: key-split needs the full mix)
  float tps[8][8], psl[8], mh[8];
  const int qlo = q0 + quad * 4;
  const float maxd = (float)((qlo + 3 > 1023 - qlo) ? qlo + 3 : 1023 - qlo);
  #pragma unroll
  for (int g = 0; g < 8; ++g) {
    float ps = 0.f;
    #pragma unroll
    for (int h = 0; h < 8; ++h) {
      float tv = thpre[g * 8 + h] * invs;
      tps[g][h] = tv;
      ps += tv * (1.0f / (float)(2 << h));   // slope_h = 2^-(h+1)
    }
    psl[g] = ps;
    mh[g] = 8.0f + fmaxf(0.f, -ps * maxd);
  }

  const ushort_t* kbase = Kf + (size_t)n * (65 * 16 * 512) + l * 8;

  // ---------------- pass 1: z (key-split, no barriers) ----------------
  float z_[8][4];
  #pragma unroll
  for (int g = 0; g < 8; ++g)
    #pragma unroll
    for (int r = 0; r < 4; ++r) z_[g][r] = 0.f;

  for (int s = w; s < 65; s += 4) {
    const ushort_t* kp = kbase + (size_t)s * 8192;
    short8 kf0[16];
    #pragma unroll
    for (int c = 0; c < 16; ++c) kf0[c] = *(const short8*)(kp + c * 512);
    float sm[8][4];
    const bool alibi = (s < 64);
    #pragma unroll
    for (int r = 0; r < 4; ++r) {
      const float dist = fabsf((float)(q0 + quad * 4 + r - (s * 16 + lm)));
      #pragma unroll
      for (int g = 0; g < 8; ++g) sm[g][r] = alibi ? -dist * psl[g] : 0.f;
    }
    #pragma unroll
    for (int h = 0; h < 8; ++h) {
      floatx4 e = (floatx4){0.f, 0.f, 0.f, 0.f};
      e = __builtin_amdgcn_mfma_f32_16x16x32_bf16(qf[2 * h],     kf0[2 * h],     e, 0, 0, 0);
      e = __builtin_amdgcn_mfma_f32_16x16x32_bf16(qf[2 * h + 1], kf0[2 * h + 1], e, 0, 0, 0);
      #pragma unroll
      for (int g = 0; g < 8; ++g)
        #pragma unroll
        for (int r = 0; r < 4; ++r) sm[g][r] += tps[g][h] * e[r];
    }
    #pragma unroll
    for (int g = 0; g < 8; ++g)
      #pragma unroll
      for (int r = 0; r < 4; ++r) z_[g][r] += __expf(sm[g][r] - mh[g]);
  }
  #pragma unroll
  for (int off = 1; off < 16; off <<= 1)
    #pragma unroll
    for (int g = 0; g < 8; ++g)
      #pragma unroll
      for (int r = 0; r < 4; ++r) z_[g][r] += __shfl_xor(z_[g][r], off);
  if (lm == 0) {
    #pragma unroll
    for (int g = 0; g < 8; ++g)
      #pragma unroll
      for (int r = 0; r < 4; ++r)
        zred[(w * 8 + g) * 16 + quad * 4 + r] = z_[g][r];
  }
  __syncthreads();
  if (t < 128)
    zil[t] = 1.0f / (zred[t] + zred[128 + t] + zred[256 + t] + zred[384 + t]);
  __syncthreads();

  // tz[gg][g] = tpost[(w*2+gg)][g] / z[g][q=lm]  (AV A-frag lane's q-row = lm)
  float tz[2][8];
  #pragma unroll
  for (int gg = 0; gg < 2; ++gg)
    #pragma unroll
    for (int g = 0; g < 8; ++g)
      tz[gg][g] = thpost[(w * 2 + gg) * 8 + g] * zil[g * 16 + lm];

  // ---------------- pass 2: P~ + AV (2 barriers per 64-key super) -------
  floatx4 o_[2][4];
  #pragma unroll
  for (int gg = 0; gg < 2; ++gg)
    #pragma unroll
    for (int ch = 0; ch < 4; ++ch) o_[gg][ch] = (floatx4){0.f, 0.f, 0.f, 0.f};

  for (int ss = 0; ss < 17; ++ss) {
    const int s = ss * 4 + w;
    __syncthreads();                 // previous super's Ps fully consumed
    if (s < 65) {
      const ushort_t* kp = kbase + (size_t)s * 8192;
      short8 kf0[16];
      #pragma unroll
      for (int c = 0; c < 16; ++c) kf0[c] = *(const short8*)(kp + c * 512);
      float sm[8][4];
      const bool alibi = (s < 64);
      #pragma unroll
      for (int r = 0; r < 4; ++r) {
        const float dist = fabsf((float)(q0 + quad * 4 + r - (s * 16 + lm)));
        #pragma unroll
        for (int g = 0; g < 8; ++g) sm[g][r] = alibi ? -dist * psl[g] : 0.f;
      }
      #pragma unroll
      for (int h = 0; h < 8; ++h) {
        floatx4 e = (floatx4){0.f, 0.f, 0.f, 0.f};
        e = __builtin_amdgcn_mfma_f32_16x16x32_bf16(qf[2 * h],     kf0[2 * h],     e, 0, 0, 0);
        e = __builtin_amdgcn_mfma_f32_16x16x32_bf16(qf[2 * h + 1], kf0[2 * h + 1], e, 0, 0, 0);
        #pragma unroll
        for (int g = 0; g < 8; ++g)
          #pragma unroll
          for (int r = 0; r < 4; ++r) sm[g][r] += tps[g][h] * e[r];
      }
      #pragma unroll
      for (int g = 0; g < 8; ++g)
        #pragma unroll
        for (int r = 0; r < 4; ++r)
          Ps[(g * 16 + quad * 4 + r) * 68 + w * 16 + lm] =
              __expf(sm[g][r] - mh[g]);
    } else {
      #pragma unroll
      for (int g = 0; g < 8; ++g)
        #pragma unroll
        for (int r = 0; r < 4; ++r)
          Ps[(g * 16 + quad * 4 + r) * 68 + w * 16 + lm] = 0.f;
    }
    __syncthreads();                 // Ps ready for all 64 keys
    const ushort_t* vbase = Vf + ((size_t)(n * 17 + ss) * 32) * 1024 + l * 8;
    #pragma unroll
    for (int c32 = 0; c32 < 2; ++c32) {
      float pm[2][8];
      #pragma unroll
      for (int gg = 0; gg < 2; ++gg)
        #pragma unroll
        for (int j = 0; j < 8; ++j) pm[gg][j] = 0.f;
      #pragma unroll
      for (int g = 0; g < 8; ++g) {
        const float4 pa = *(const float4*)&Ps[(g * 16 + lm) * 68 + c32 * 32 + quad * 8];
        const float4 pb = *(const float4*)&Ps[(g * 16 + lm) * 68 + c32 * 32 + quad * 8 + 4];
        #pragma unroll
        for (int gg = 0; gg < 2; ++gg) {
          const float tw = tz[gg][g];
          pm[gg][0] += tw * pa.x; pm[gg][1] += tw * pa.y;
          pm[gg][2] += tw * pa.z; pm[gg][3] += tw * pa.w;
          pm[gg][4] += tw * pb.x; pm[gg][5] += tw * pb.y;
          pm[gg][6] += tw * pb.z; pm[gg][7] += tw * pb.w;
        }
      }
      short8 pk2[2];
      #pragma unroll
      for (int gg = 0; gg < 2; ++gg)
        #pragma unroll
        for (int j = 0; j < 8; ++j) pk2[gg][j] = (short)f2bf(pm[gg][j]);
      #pragma unroll
      for (int gg = 0; gg < 2; ++gg)
        #pragma unroll
        for (int ch = 0; ch < 4; ++ch) {
          const int dc = (w * 2 + gg) * 4 + ch;
          const short8 vf0 = *(const short8*)(vbase + dc * 1024 + c32 * 512);
          o_[gg][ch] = __builtin_amdgcn_mfma_f32_16x16x32_bf16(
              pk2[gg], vf0, o_[gg][ch], 0, 0, 0);
        }
    }
  }

  // epilogue: C col=lm -> d, row = quad*4+r -> q
  #pragma unroll
  for (int gg = 0; gg < 2; ++gg)
    #pragma unroll
    for (int ch = 0; ch < 4; ++ch) {
      const int d = (w * 2 + gg) * 64 + ch * 16 + lm;
      #pragma unroll
      for (int r = 0; r < 4; ++r)
        aob[((size_t)(n * LQ + q0 + quad * 4 + r)) * 512 + d] = f2bf(o_[gg][ch][r]);
    }
}

// ---------------------------------------------------------------------------
// swiglu: h = silu(h1+b1)*(h2+b2), raw [8192][4096] bf16 -> padded bf16
// ---------------------------------------------------------------------------
__global__ __launch_bounds__(256) void swiglu_kernel(
    const ushort_t* __restrict__ hraw, const float* __restrict__ bias,
    ushort_t* __restrict__ hpad)
{
  const int tok = blockIdx.x;
  const int n = tok >> 10, l = tok & 1023;
  const size_t src = (size_t)tok * 4096;
  const size_t dst = ((size_t)n * 1026 + l + 1) * 2048;
  for (int c = threadIdx.x; c < 2048; c += 256) {
    float h1 = bf2f(hraw[src + c]) + bias[c];
    float h2 = bf2f(hraw[src + 2048 + c]) + bias[2048 + c];
    float s = h1 / (1.f + __expf(-h1));
    hpad[dst + c] = f2bf(s * h2);
  }
}

__global__ __launch_bounds__(256) void zero_pads_kernel(
    ushort_t* __restrict__ x1b, ushort_t* __restrict__ hpad)
{
  const int b = blockIdx.x;
  const int n = b >> 1, side = b & 1;
  const size_t r = (size_t)n * 1026 + side * 1025;
  ushort2 z; z.x = 0; z.y = 0;
  *(ushort2*)&x1b[r * 512 + threadIdx.x * 2] = z;
  #pragma unroll
  for (int i = 0; i < 4; ++i)
    *(ushort2*)&hpad[r * 2048 + (threadIdx.x + 256 * i) * 2] = z;
}

// ---------------------------------------------------------------------------
// LayerNorm (fp32) + optional bf16 padded copy
// ---------------------------------------------------------------------------
__global__ __launch_bounds__(256) void ln_kernel(
    const float* __restrict__ in, const float* __restrict__ res,
    const float* __restrict__ g, const float* __restrict__ b,
    float* __restrict__ outp, ushort_t* __restrict__ bfout)
{
  const int w = threadIdx.x >> 6, lane = threadIdx.x & 63;
  const int tok = blockIdx.x * 4 + w;
  const size_t base = (size_t)tok * CH;
  float4 v0 = *(const float4*)&in[base + (lane << 2)];
  float4 v1 = *(const float4*)&in[base + 256 + (lane << 2)];
  if (res != nullptr) {
    float4 r0 = *(const float4*)&res[base + (lane << 2)];
    float4 r1 = *(const float4*)&res[base + 256 + (lane << 2)];
    v0.x += r0.x; v0.y += r0.y; v0.z += r0.z; v0.w += r0.w;
    v1.x += r1.x; v1.y += r1.y; v1.z += r1.z; v1.w += r1.w;
  }
  float s = v0.x + v0.y + v0.z + v0.w + v1.x + v1.y + v1.z + v1.w;
  #pragma unroll
  for (int off = 32; off > 0; off >>= 1) s += __shfl_xor(s, off);
  const float mu = s * (1.f / 512.f);
  float d0 = v0.x - mu, d1 = v0.y - mu, d2 = v0.z - mu, d3 = v0.w - mu;
  float d4 = v1.x - mu, d5 = v1.y - mu, d6 = v1.z - mu, d7 = v1.w - mu;
  float vs = d0*d0 + d1*d1 + d2*d2 + d3*d3 + d4*d4 + d5*d5 + d6*d6 + d7*d7;
  #pragma unroll
  for (int off = 32; off > 0; off >>= 1) vs += __shfl_xor(vs, off);
  const float r = rsqrtf(vs * (1.f / 512.f) + 1e-5f);
  float4 ga = *(const float4*)&g[(lane << 2)];
  float4 gb = *(const float4*)&g[256 + (lane << 2)];
  float4 ba = *(const float4*)&b[(lane << 2)];
  float4 bb = *(const float4*)&b[256 + (lane << 2)];
  float4 o0, o1;
  o0.x = d0 * r * ga.x + ba.x; o0.y = d1 * r * ga.y + ba.y;
  o0.z = d2 * r * ga.z + ba.z; o0.w = d3 * r * ga.w + ba.w;
  o1.x = d4 * r * gb.x + bb.x; o1.y = d5 * r * gb.y + bb.y;
  o1.z = d6 * r * gb.z + bb.z; o1.w = d7 * r * gb.w + bb.w;
  *(float4*)&outp[base + (lane << 2)] = o0;
  *(float4*)&outp[base + 256 + (lane << 2)] = o1;
  if (bfout != nullptr) {
    const int n = tok >> 10, ll = tok & 1023;
    const size_t bb2 = ((size_t)n * 1026 + ll + 1) * 512;
    ushort4 u0 = make_ushort4(f2bf(o0.x), f2bf(o0.y), f2bf(o0.z), f2bf(o0.w));
    ushort4 u1 = make_ushort4(f2bf(o1.x), f2bf(o1.y), f2bf(o1.z), f2bf(o1.w));
    *(ushort4*)&bfout[bb2 + (lane << 2)] = u0;
    *(ushort4*)&bfout[bb2 + 256 + (lane << 2)] = u1;
  }
}

// ---------------------------------------------------------------------------
extern "C" void kernel_launch(void* const* d_in, const int* in_sizes, int n_in,
                              void* d_out, int out_size, void* d_ws, size_t ws_size,
                              hipStream_t stream)
{
  (void)in_sizes; (void)n_in; (void)out_size; (void)ws_size;
  const float* x      = (const float*)d_in[0];
  const float* Wq     = (const float*)d_in[1];
  const float* Wk     = (const float*)d_in[2];
  const float* Wv     = (const float*)d_in[3];
  const float* Wo     = (const float*)d_in[4];
  const float* bo     = (const float*)d_in[5];
  const float* th_pre = (const float*)d_in[6];
  const float* th_post= (const float*)d_in[7];
  const float* p_keys = (const float*)d_in[8];
  const float* p_vals = (const float*)d_in[9];
  const float* c1w    = (const float*)d_in[10];
  const float* c1b    = (const float*)d_in[11];
  const float* c2w    = (const float*)d_in[12];
  const float* c2b    = (const float*)d_in[13];
  const float* ln1g   = (const float*)d_in[14];
  const float* ln1b   = (const float*)d_in[15];
  const float* ln2g   = (const float*)d_in[16];
  const float* ln2b   = (const float*)d_in[17];

  float* ws  = (float*)d_ws;
  float* out = (float*)d_out;

  ushort_t* Qb   = (ushort_t*)(ws + O_QB);
  ushort_t* Kb   = (ushort_t*)(ws + O_KB);
  ushort_t* Vb   = (ushort_t*)(ws + O_VB);
  ushort_t* Kf   = (ushort_t*)(ws + O_KF);
  ushort_t* Vf   = (ushort_t*)(ws + O_VF);
  ushort_t* aob  = (ushort_t*)(ws + O_AOB);
  float*    abf  = ws + O_AF;
  float*    fbf  = abf;
  ushort_t* x1b  = (ushort_t*)(ws + O_X1B);
  ushort_t* hpad = (ushort_t*)(ws + O_HPAD);
  ushort_t* hraw = (ushort_t*)ws;         // overlays dead attn buffers
  ushort_t* w1p  = (ushort_t*)(ws + O_W1);
  ushort_t* w2p  = (ushort_t*)(ws + O_W2);
  ushort_t* wop  = (ushort_t*)(ws + O_WO);

  pack_bf16_kernel<<<4096, 256, 0, stream>>>(c1w, w1p, 1536, 3, 9);
  pack_bf16_kernel<<<512,  256, 0, stream>>>(c2w, w2p, 6144, 3, 11);
  pack_bf16_kernel<<<512,  256, 0, stream>>>(Wo,  wop, 512,  1, 9);

  qkv_mfma<<<dim3(128, 3), 256, 0, stream>>>(x, Wq, Wk, Wv, Qb, Kb, Vb);
  persist_kernel<<<256, 256, 0, stream>>>(p_keys, p_vals, Kb, Vb);
  kfrag_kernel<<<dim3(65, 8), 256, 0, stream>>>(Kb, Kf);
  vfrag_kernel<<<dim3(34, 8), 256, 0, stream>>>(Vb, Vf);

  attn_v4<<<dim3(64, 8), 256, 0, stream>>>(Qb, Kf, Vf, th_pre, th_post, aob);

  // Wo: M=8192 N=512 K=512, +bias +residual(x) -> abf fp32
  mfma_gemm<2><<<dim3(64, 4), 256, 0, stream>>>(
      aob, wop, 512, 1024 * 512, 512, 512, bo, x, abf, nullptr);

  ln_kernel<<<2048, 256, 0, stream>>>(abf, nullptr, ln1g, ln1b, out, x1b);
  zero_pads_kernel<<<16, 256, 0, stream>>>(x1b, hpad);

  // conv1: M=8192 N=4096 K=1536 -> hraw bf16
  mfma_gemm<0><<<dim3(64, 32), 256, 0, stream>>>(
      x1b, w1p, 1536, 1026 * 512, 512, 4096, nullptr, nullptr, nullptr, hraw);

  swiglu_kernel<<<8192, 256, 0, stream>>>(hraw, c1b, hpad);

  // conv2: M=8192 N=512 K=6144, +bias -> fbf fp32
  mfma_gemm<1><<<dim3(64, 4), 256, 0, stream>>>(
      hpad, w2p, 6144, 1026 * 2048, 2048, 512, c2b, nullptr, fbf, nullptr);

  ln_kernel<<<2048, 256, 0, stream>>>(fbf, out, ln2g, ln2b, out, nullptr);
}

// Round 7
// 673.982 us; speedup vs baseline: 1.1907x; 1.0806x over previous
//
#include <hip/hip_runtime.h>
#include <cstddef>
#include <cstdint>

#define NB   8
#define LQ   1024
#define CH   512
#define HHE  8
#define HDD  64
#define PPM  16
#define LP   1040     // L + P
#define HID  2048

typedef unsigned short ushort_t;
typedef __attribute__((ext_vector_type(8))) short short8;
typedef __attribute__((ext_vector_type(4))) float floatx4;

// ---- workspace layout (float element offsets) ----
static const size_t O_QB   = 0;          // Qb bf16   (2,097,152 fl)
static const size_t O_KB   = 2097152;    // Kb bf16 token-major (2,129,920 fl)
static const size_t O_VB   = 4227072;    // Vb bf16 token-major (2,129,920 fl)
static const size_t O_KF   = 6356992;    // Kf bf16 frag-order  (2,129,920 fl)
static const size_t O_VF   = 8486912;    // Vf bf16 frag-order  (2,228,224 fl)
static const size_t O_AOB  = 10715136;   // aob bf16  (2,097,152 fl)
static const size_t O_AF   = 12812288;   // abf/fbf fp32 (4,194,304 fl)
// hraw bf16 overlays floats [0 .. 16,777,216)
static const size_t O_X1B  = 17006592;   // x1b padded bf16 (2,101,248 fl)
static const size_t O_HPAD = 19107840;   // hpad bf16 (8,404,992 fl)
static const size_t O_W1   = 27512832;   // w1 bf16   (3,145,728 fl)
static const size_t O_W2   = 30658560;   // w2 bf16   (1,572,864 fl)
static const size_t O_WO   = 32231424;   // wo bf16   (131,072 fl)
// total 32,362,496 floats = 129.4 MB

__device__ __forceinline__ ushort_t f2bf(float f) {
  uint32_t u = __float_as_uint(f);
  u += 0x7FFFu + ((u >> 16) & 1u);
  return (ushort_t)(u >> 16);
}
__device__ __forceinline__ float bf2f(ushort_t h) {
  return __uint_as_float(((uint32_t)h) << 16);
}

__device__ __forceinline__ void async16(ushort_t* lds, const ushort_t* g) {
  __builtin_amdgcn_global_load_lds(
      (const __attribute__((address_space(1))) void*)g,
      (__attribute__((address_space(3))) void*)lds, 16, 0, 0);
}

// ---------------------------------------------------------------------------
// weight pack to bf16 [oc][k], k = dl*IC + ic; src[oc*K + ic*KD + dl]
// ---------------------------------------------------------------------------
__global__ __launch_bounds__(256) void pack_bf16_kernel(
    const float* __restrict__ src, ushort_t* __restrict__ dst,
    int K, int KD, int icShift)
{
  const int oc = blockIdx.x;
  const int icMask = (1 << icShift) - 1;
  for (int k = threadIdx.x; k < K; k += 256) {
    int ic = k & icMask, dl = k >> icShift;
    dst[(size_t)oc * K + k] = f2bf(src[(size_t)oc * K + ic * KD + dl]);
  }
}

// ---------------------------------------------------------------------------
// Generic bf16 MFMA GEMM, 128x128 tile, BK=32, global_load_lds staging.
// ---------------------------------------------------------------------------
template<int EPI>
__global__ __launch_bounds__(256, 2) void mfma_gemm(
    const ushort_t* __restrict__ Ab, const ushort_t* __restrict__ Bb,
    int K, int BS, int P, int NOUT,
    const float* __restrict__ bias, const float* __restrict__ res,
    float* __restrict__ outf, ushort_t* __restrict__ outh)
{
  __shared__ ushort_t As[128 * 32];
  __shared__ ushort_t Bs[128 * 32];
  const int t = threadIdx.x;
  const int w = t >> 6, l = t & 63;
  const int m0 = blockIdx.x * 128, n0 = blockIdx.y * 128;

  const int sub = l >> 2;
  const int kc8 = (l & 3) * 8;
  const ushort_t* aptr[2];
  const ushort_t* bptr[2];
  #pragma unroll
  for (int c = 0; c < 2; ++c) {
    int arow = m0 + w * 32 + c * 16 + sub;
    aptr[c] = Ab + (size_t)(arow >> 10) * BS + (size_t)(arow & 1023) * P + kc8;
    int brow = n0 + w * 32 + c * 16 + sub;
    bptr[c] = Bb + (size_t)brow * K + kc8;
  }

  const int wm = w >> 1, wn = w & 1;
  const int lm = l & 15, q = l >> 4;
  floatx4 acc[4][4];
  #pragma unroll
  for (int i = 0; i < 4; ++i)
    #pragma unroll
    for (int j = 0; j < 4; ++j)
      acc[i][j] = (floatx4){0.f, 0.f, 0.f, 0.f};

  const int kIters = K >> 5;
  for (int kt = 0; kt < kIters; ++kt) {
    __syncthreads();
    async16(&As[w * 1024 +   0], aptr[0]);
    async16(&As[w * 1024 + 512], aptr[1]);
    async16(&Bs[w * 1024 +   0], bptr[0]);
    async16(&Bs[w * 1024 + 512], bptr[1]);
    aptr[0] += 32; aptr[1] += 32; bptr[0] += 32; bptr[1] += 32;
    __syncthreads();
    short8 af[4], bf[4];
    #pragma unroll
    for (int i = 0; i < 4; ++i)
      af[i] = *(const short8*)&As[(wm * 64 + i * 16 + lm) * 32 + q * 8];
    #pragma unroll
    for (int i = 0; i < 4; ++i)
      bf[i] = *(const short8*)&Bs[(wn * 64 + i * 16 + lm) * 32 + q * 8];
    #pragma unroll
    for (int i = 0; i < 4; ++i)
      #pragma unroll
      for (int j = 0; j < 4; ++j)
        acc[i][j] = __builtin_amdgcn_mfma_f32_16x16x32_bf16(af[i], bf[j], acc[i][j], 0, 0, 0);
  }

  #pragma unroll
  for (int i = 0; i < 4; ++i) {
    #pragma unroll
    for (int j = 0; j < 4; ++j) {
      const int mbase = m0 + wm * 64 + i * 16 + q * 4;
      const int n = n0 + wn * 64 + j * 16 + lm;
      #pragma unroll
      for (int r = 0; r < 4; ++r) {
        const int m = mbase + r;
        float v = acc[i][j][r];
        if (EPI == 0) {
          outh[(size_t)m * NOUT + n] = f2bf(v);
        } else if (EPI == 1) {
          outf[(size_t)m * NOUT + n] = v + bias[n];
        } else {
          outf[(size_t)m * NOUT + n] = v + bias[n] + res[(size_t)m * NOUT + n];
        }
      }
    }
  }
}

// ---------------------------------------------------------------------------
// QKV projection via MFMA. grid (128, 3)
// ---------------------------------------------------------------------------
__global__ __launch_bounds__(256) void qkv_mfma(
    const float* __restrict__ x,
    const float* __restrict__ Wq, const float* __restrict__ Wk, const float* __restrict__ Wv,
    ushort_t* __restrict__ qo, ushort_t* __restrict__ ko, ushort_t* __restrict__ vo)
{
  __shared__ ushort_t Ws[8 * 512];
  const int mat = blockIdx.y;
  const float* __restrict__ W = (mat == 0) ? Wq : (mat == 1) ? Wk : Wv;
  const int t = threadIdx.x;

  for (int e = t; e < 4096; e += 256) {
    const int oc = e >> 6, ic = e & 63;
    const int nt = oc >> 4, lmm = oc & 15, s = ic >> 5, qd = (ic >> 3) & 3, j = ic & 7;
    Ws[(((nt * 2 + s) * 4 + qd) * 16 + lmm) * 8 + j] = f2bf(W[e]);
  }

  const int w = t >> 6, l = t & 63;
  const int lm = l & 15, quad = l >> 4;
  const int tok0 = blockIdx.x * 64 + w * 16;

  short8 af[16];
  {
    const float* xrow = x + (size_t)(tok0 + lm) * CH + quad * 8;
    #pragma unroll
    for (int h = 0; h < 8; ++h) {
      #pragma unroll
      for (int s = 0; s < 2; ++s) {
        const float4 a = *(const float4*)(xrow + h * 64 + s * 32);
        const float4 b = *(const float4*)(xrow + h * 64 + s * 32 + 4);
        short8 f;
        f[0] = (short)f2bf(a.x); f[1] = (short)f2bf(a.y);
        f[2] = (short)f2bf(a.z); f[3] = (short)f2bf(a.w);
        f[4] = (short)f2bf(b.x); f[5] = (short)f2bf(b.y);
        f[6] = (short)f2bf(b.z); f[7] = (short)f2bf(b.w);
        af[h * 2 + s] = f;
      }
    }
  }
  __syncthreads();

  short8 bfr[8];
  #pragma unroll
  for (int nt = 0; nt < 4; ++nt)
    #pragma unroll
    for (int s = 0; s < 2; ++s)
      bfr[nt * 2 + s] = *(const short8*)&Ws[((nt * 2 + s) * 64 + l) * 8];

  const int n = tok0 >> 10, lpos = tok0 & 1023;
  ushort_t* outp;
  size_t base;
  if (mat == 0) { base = ((size_t)n * LQ + lpos) * CH; outp = qo; }
  else          { base = ((size_t)n * LP + lpos) * CH; outp = (mat == 1) ? ko : vo; }

  #pragma unroll
  for (int h = 0; h < 8; ++h) {
    floatx4 acc[4];
    #pragma unroll
    for (int nt = 0; nt < 4; ++nt) acc[nt] = (floatx4){0.f, 0.f, 0.f, 0.f};
    #pragma unroll
    for (int nt = 0; nt < 4; ++nt)
      #pragma unroll
      for (int s = 0; s < 2; ++s)
        acc[nt] = __builtin_amdgcn_mfma_f32_16x16x32_bf16(
            af[h * 2 + s], bfr[nt * 2 + s], acc[nt], 0, 0, 0);
    #pragma unroll
    for (int nt = 0; nt < 4; ++nt)
      #pragma unroll
      for (int r = 0; r < 4; ++r)
        outp[base + (size_t)(quad * 4 + r) * CH + h * 64 + nt * 16 + lm] =
            f2bf(acc[nt][r]);
  }
}

__global__ __launch_bounds__(256) void persist_kernel(
    const float* __restrict__ pk, const float* __restrict__ pv,
    ushort_t* __restrict__ ko, ushort_t* __restrict__ vo)
{
  const int t = blockIdx.x * 256 + threadIdx.x;
  const int n = t >> 13, p = (t >> 9) & 15, c = t & 511, d = c & 63;
  const size_t o = ((size_t)n * LP + LQ + p) * CH + c;
  ko[o] = f2bf(pk[p * 64 + d]);
  vo[o] = f2bf(pv[p * 64 + d]);
}

// ---------------------------------------------------------------------------
// K repack to fragment-order: Kf[((n*65+s)*16+c)*512 + lane*8 + j]
// ---------------------------------------------------------------------------
__global__ __launch_bounds__(256) void kfrag_kernel(
    const ushort_t* __restrict__ Kb, ushort_t* __restrict__ Kf)
{
  __shared__ ushort_t Ls[16 * 520];
  const int n = blockIdx.y, s = blockIdx.x;
  const int t = threadIdx.x;
  #pragma unroll
  for (int it = 0; it < 4; ++it) {
    int cid = t + 256 * it;
    int row = cid >> 6, cc = cid & 63;
    *(short8*)&Ls[row * 520 + cc * 8] =
        *(const short8*)&Kb[((size_t)(n * LP + s * 16 + row)) * 512 + cc * 8];
  }
  __syncthreads();
  const int lane = t & 63, quad = lane >> 4, lm = lane & 15;
  #pragma unroll
  for (int it = 0; it < 4; ++it) {
    int c = (t >> 6) + 4 * it;
    short8 v = *(const short8*)&Ls[lm * 520 + c * 32 + quad * 8];
    *(short8*)&Kf[((size_t)(n * 65 + s) * 16 + c) * 512 + lane * 8] = v;
  }
}

// ---------------------------------------------------------------------------
// V repack to AV-fragment-order
// ---------------------------------------------------------------------------
__global__ __launch_bounds__(256) void vfrag_kernel(
    const ushort_t* __restrict__ Vb, ushort_t* __restrict__ Vf)
{
  __shared__ ushort_t Ls[32 * 520];
  const int n = blockIdx.y, bx = blockIdx.x;
  const int k0 = bx * 32;
  const int t = threadIdx.x;
  #pragma unroll
  for (int it = 0; it < 8; ++it) {
    int cid = t + 256 * it;
    int row = cid >> 6, cc = cid & 63;
    short8 v = {};
    if (k0 + row < LP)
      v = *(const short8*)&Vb[((size_t)(n * LP + k0 + row)) * 512 + cc * 8];
    *(short8*)&Ls[row * 520 + cc * 8] = v;
  }
  __syncthreads();
  const int lane = t & 63, quad = lane >> 4, lm = lane & 15;
  const int ss = bx >> 1, c32 = bx & 1;
  #pragma unroll
  for (int it = 0; it < 8; ++it) {
    int dc = (t >> 6) + 4 * it;
    short8 v;
    #pragma unroll
    for (int j = 0; j < 8; ++j)
      v[j] = (short)Ls[(quad * 8 + j) * 520 + dc * 16 + lm];
    *(short8*)&Vf[(((size_t)(n * 17 + ss) * 32 + dc) * 2 + c32) * 512 + lane * 8] = v;
  }
}

// ---------------------------------------------------------------------------
// MFMA flash attention v5 — v4 + XCD-clustered grid: flat 512 blocks,
// n = bid & 7 so (with round-robin block->XCD dispatch) all 64 q-tiles of a
// batch land on one XCD and K/V live in its L2 (2.1 MB << 4 MB).
// ---------------------------------------------------------------------------
__global__ __launch_bounds__(256, 2) void attn_v5(
    const ushort_t* __restrict__ Qb, const ushort_t* __restrict__ Kf,
    const ushort_t* __restrict__ Vf,
    const float* __restrict__ thpre, const float* __restrict__ thpost,
    ushort_t* __restrict__ aob)
{
  __shared__ float Ps[8 * 16 * 68];   // P~ [g][q][64k + pad4], fp32
  __shared__ float zred[4 * 8 * 16];
  __shared__ float zil[8 * 16];
  const int bid = blockIdx.x;
  const int n = bid & 7, q0 = (bid >> 3) * 16;   // XCD-cluster by batch
  const int t = threadIdx.x, w = t >> 6, l = t & 63;
  const int lm = l & 15, quad = l >> 4;
  const float invs = 0.044194173824159216f;  // 1/sqrt(512)

  // persistent Q A-fragments: A[m=lm][k=c*32+quad*8+j]
  short8 qf[16];
  {
    const ushort_t* qrow = Qb + ((size_t)(n * LQ + q0 + lm)) * 512 + quad * 8;
    #pragma unroll
    for (int c = 0; c < 16; ++c) qf[c] = *(const short8*)(qrow + c * 32);
  }

  // pre-softmax talking heads (all 8 g: key-split needs the full mix)
  float tps[8][8], psl[8], mh[8];
  const int qlo = q0 + quad * 4;
  const float maxd = (float)((qlo + 3 > 1023 - qlo) ? qlo + 3 : 1023 - qlo);
  #pragma unroll
  for (int g = 0; g < 8; ++g) {
    float ps = 0.f;
    #pragma unroll
    for (int h = 0; h < 8; ++h) {
      float tv = thpre[g * 8 + h] * invs;
      tps[g][h] = tv;
      ps += tv * (1.0f / (float)(2 << h));   // slope_h = 2^-(h+1)
    }
    psl[g] = ps;
    mh[g] = 8.0f + fmaxf(0.f, -ps * maxd);
  }

  const ushort_t* kbase = Kf + (size_t)n * (65 * 16 * 512) + l * 8;

  // ---------------- pass 1: z (key-split, no barriers) ----------------
  float z_[8][4];
  #pragma unroll
  for (int g = 0; g < 8; ++g)
    #pragma unroll
    for (int r = 0; r < 4; ++r) z_[g][r] = 0.f;

  for (int s = w; s < 65; s += 4) {
    const ushort_t* kp = kbase + (size_t)s * 8192;
    short8 kf0[16];
    #pragma unroll
    for (int c = 0; c < 16; ++c) kf0[c] = *(const short8*)(kp + c * 512);
    float sm[8][4];
    const bool alibi = (s < 64);
    #pragma unroll
    for (int r = 0; r < 4; ++r) {
      const float dist = fabsf((float)(q0 + quad * 4 + r - (s * 16 + lm)));
      #pragma unroll
      for (int g = 0; g < 8; ++g) sm[g][r] = alibi ? -dist * psl[g] : 0.f;
    }
    #pragma unroll
    for (int h = 0; h < 8; ++h) {
      floatx4 e = (floatx4){0.f, 0.f, 0.f, 0.f};
      e = __builtin_amdgcn_mfma_f32_16x16x32_bf16(qf[2 * h],     kf0[2 * h],     e, 0, 0, 0);
      e = __builtin_amdgcn_mfma_f32_16x16x32_bf16(qf[2 * h + 1], kf0[2 * h + 1], e, 0, 0, 0);
      #pragma unroll
      for (int g = 0; g < 8; ++g)
        #pragma unroll
        for (int r = 0; r < 4; ++r) sm[g][r] += tps[g][h] * e[r];
    }
    #pragma unroll
    for (int g = 0; g < 8; ++g)
      #pragma unroll
      for (int r = 0; r < 4; ++r) z_[g][r] += __expf(sm[g][r] - mh[g]);
  }
  #pragma unroll
  for (int off = 1; off < 16; off <<= 1)
    #pragma unroll
    for (int g = 0; g < 8; ++g)
      #pragma unroll
      for (int r = 0; r < 4; ++r) z_[g][r] += __shfl_xor(z_[g][r], off);
  if (lm == 0) {
    #pragma unroll
    for (int g = 0; g < 8; ++g)
      #pragma unroll
      for (int r = 0; r < 4; ++r)
        zred[(w * 8 + g) * 16 + quad * 4 + r] = z_[g][r];
  }
  __syncthreads();
  if (t < 128)
    zil[t] = 1.0f / (zred[t] + zred[128 + t] + zred[256 + t] + zred[384 + t]);
  __syncthreads();

  float tz[2][8];
  #pragma unroll
  for (int gg = 0; gg < 2; ++gg)
    #pragma unroll
    for (int g = 0; g < 8; ++g)
      tz[gg][g] = thpost[(w * 2 + gg) * 8 + g] * zil[g * 16 + lm];

  // ---------------- pass 2: P~ + AV (2 barriers per 64-key super) -------
  floatx4 o_[2][4];
  #pragma unroll
  for (int gg = 0; gg < 2; ++gg)
    #pragma unroll
    for (int ch = 0; ch < 4; ++ch) o_[gg][ch] = (floatx4){0.f, 0.f, 0.f, 0.f};

  for (int ss = 0; ss < 17; ++ss) {
    const int s = ss * 4 + w;
    __syncthreads();
    if (s < 65) {
      const ushort_t* kp = kbase + (size_t)s * 8192;
      short8 kf0[16];
      #pragma unroll
      for (int c = 0; c < 16; ++c) kf0[c] = *(const short8*)(kp + c * 512);
      float sm[8][4];
      const bool alibi = (s < 64);
      #pragma unroll
      for (int r = 0; r < 4; ++r) {
        const float dist = fabsf((float)(q0 + quad * 4 + r - (s * 16 + lm)));
        #pragma unroll
        for (int g = 0; g < 8; ++g) sm[g][r] = alibi ? -dist * psl[g] : 0.f;
      }
      #pragma unroll
      for (int h = 0; h < 8; ++h) {
        floatx4 e = (floatx4){0.f, 0.f, 0.f, 0.f};
        e = __builtin_amdgcn_mfma_f32_16x16x32_bf16(qf[2 * h],     kf0[2 * h],     e, 0, 0, 0);
        e = __builtin_amdgcn_mfma_f32_16x16x32_bf16(qf[2 * h + 1], kf0[2 * h + 1], e, 0, 0, 0);
        #pragma unroll
        for (int g = 0; g < 8; ++g)
          #pragma unroll
          for (int r = 0; r < 4; ++r) sm[g][r] += tps[g][h] * e[r];
      }
      #pragma unroll
      for (int g = 0; g < 8; ++g)
        #pragma unroll
        for (int r = 0; r < 4; ++r)
          Ps[(g * 16 + quad * 4 + r) * 68 + w * 16 + lm] =
              __expf(sm[g][r] - mh[g]);
    } else {
      #pragma unroll
      for (int g = 0; g < 8; ++g)
        #pragma unroll
        for (int r = 0; r < 4; ++r)
          Ps[(g * 16 + quad * 4 + r) * 68 + w * 16 + lm] = 0.f;
    }
    __syncthreads();
    const ushort_t* vbase = Vf + ((size_t)(n * 17 + ss) * 32) * 1024 + l * 8;
    #pragma unroll
    for (int c32 = 0; c32 < 2; ++c32) {
      float pm[2][8];
      #pragma unroll
      for (int gg = 0; gg < 2; ++gg)
        #pragma unroll
        for (int j = 0; j < 8; ++j) pm[gg][j] = 0.f;
      #pragma unroll
      for (int g = 0; g < 8; ++g) {
        const float4 pa = *(const float4*)&Ps[(g * 16 + lm) * 68 + c32 * 32 + quad * 8];
        const float4 pb = *(const float4*)&Ps[(g * 16 + lm) * 68 + c32 * 32 + quad * 8 + 4];
        #pragma unroll
        for (int gg = 0; gg < 2; ++gg) {
          const float tw = tz[gg][g];
          pm[gg][0] += tw * pa.x; pm[gg][1] += tw * pa.y;
          pm[gg][2] += tw * pa.z; pm[gg][3] += tw * pa.w;
          pm[gg][4] += tw * pb.x; pm[gg][5] += tw * pb.y;
          pm[gg][6] += tw * pb.z; pm[gg][7] += tw * pb.w;
        }
      }
      short8 pk2[2];
      #pragma unroll
      for (int gg = 0; gg < 2; ++gg)
        #pragma unroll
        for (int j = 0; j < 8; ++j) pk2[gg][j] = (short)f2bf(pm[gg][j]);
      #pragma unroll
      for (int gg = 0; gg < 2; ++gg)
        #pragma unroll
        for (int ch = 0; ch < 4; ++ch) {
          const int dc = (w * 2 + gg) * 4 + ch;
          const short8 vf0 = *(const short8*)(vbase + dc * 1024 + c32 * 512);
          o_[gg][ch] = __builtin_amdgcn_mfma_f32_16x16x32_bf16(
              pk2[gg], vf0, o_[gg][ch], 0, 0, 0);
        }
    }
  }

  #pragma unroll
  for (int gg = 0; gg < 2; ++gg)
    #pragma unroll
    for (int ch = 0; ch < 4; ++ch) {
      const int d = (w * 2 + gg) * 64 + ch * 16 + lm;
      #pragma unroll
      for (int r = 0; r < 4; ++r)
        aob[((size_t)(n * LQ + q0 + quad * 4 + r)) * 512 + d] = f2bf(o_[gg][ch][r]);
    }
}

// ---------------------------------------------------------------------------
// swiglu: h = silu(h1+b1)*(h2+b2), raw [8192][4096] bf16 -> padded bf16
// ---------------------------------------------------------------------------
__global__ __launch_bounds__(256) void swiglu_kernel(
    const ushort_t* __restrict__ hraw, const float* __restrict__ bias,
    ushort_t* __restrict__ hpad)
{
  const int tok = blockIdx.x;
  const int n = tok >> 10, l = tok & 1023;
  const size_t src = (size_t)tok * 4096;
  const size_t dst = ((size_t)n * 1026 + l + 1) * 2048;
  for (int c = threadIdx.x; c < 2048; c += 256) {
    float h1 = bf2f(hraw[src + c]) + bias[c];
    float h2 = bf2f(hraw[src + 2048 + c]) + bias[2048 + c];
    float s = h1 / (1.f + __expf(-h1));
    hpad[dst + c] = f2bf(s * h2);
  }
}

__global__ __launch_bounds__(256) void zero_pads_kernel(
    ushort_t* __restrict__ x1b, ushort_t* __restrict__ hpad)
{
  const int b = blockIdx.x;
  const int n = b >> 1, side = b & 1;
  const size_t r = (size_t)n * 1026 + side * 1025;
  ushort2 z; z.x = 0; z.y = 0;
  *(ushort2*)&x1b[r * 512 + threadIdx.x * 2] = z;
  #pragma unroll
  for (int i = 0; i < 4; ++i)
    *(ushort2*)&hpad[r * 2048 + (threadIdx.x + 256 * i) * 2] = z;
}

// ---------------------------------------------------------------------------
// LayerNorm (fp32) + optional bf16 padded copy
// ---------------------------------------------------------------------------
__global__ __launch_bounds__(256) void ln_kernel(
    const float* __restrict__ in, const float* __restrict__ res,
    const float* __restrict__ g, const float* __restrict__ b,
    float* __restrict__ outp, ushort_t* __restrict__ bfout)
{
  const int w = threadIdx.x >> 6, lane = threadIdx.x & 63;
  const int tok = blockIdx.x * 4 + w;
  const size_t base = (size_t)tok * CH;
  float4 v0 = *(const float4*)&in[base + (lane << 2)];
  float4 v1 = *(const float4*)&in[base + 256 + (lane << 2)];
  if (res != nullptr) {
    float4 r0 = *(const float4*)&res[base + (lane << 2)];
    float4 r1 = *(const float4*)&res[base + 256 + (lane << 2)];
    v0.x += r0.x; v0.y += r0.y; v0.z += r0.z; v0.w += r0.w;
    v1.x += r1.x; v1.y += r1.y; v1.z += r1.z; v1.w += r1.w;
  }
  float s = v0.x + v0.y + v0.z + v0.w + v1.x + v1.y + v1.z + v1.w;
  #pragma unroll
  for (int off = 32; off > 0; off >>= 1) s += __shfl_xor(s, off);
  const float mu = s * (1.f / 512.f);
  float d0 = v0.x - mu, d1 = v0.y - mu, d2 = v0.z - mu, d3 = v0.w - mu;
  float d4 = v1.x - mu, d5 = v1.y - mu, d6 = v1.z - mu, d7 = v1.w - mu;
  float vs = d0*d0 + d1*d1 + d2*d2 + d3*d3 + d4*d4 + d5*d5 + d6*d6 + d7*d7;
  #pragma unroll
  for (int off = 32; off > 0; off >>= 1) vs += __shfl_xor(vs, off);
  const float r = rsqrtf(vs * (1.f / 512.f) + 1e-5f);
  float4 ga = *(const float4*)&g[(lane << 2)];
  float4 gb = *(const float4*)&g[256 + (lane << 2)];
  float4 ba = *(const float4*)&b[(lane << 2)];
  float4 bb = *(const float4*)&b[256 + (lane << 2)];
  float4 o0, o1;
  o0.x = d0 * r * ga.x + ba.x; o0.y = d1 * r * ga.y + ba.y;
  o0.z = d2 * r * ga.z + ba.z; o0.w = d3 * r * ga.w + ba.w;
  o1.x = d4 * r * gb.x + bb.x; o1.y = d5 * r * gb.y + bb.y;
  o1.z = d6 * r * gb.z + bb.z; o1.w = d7 * r * gb.w + bb.w;
  *(float4*)&outp[base + (lane << 2)] = o0;
  *(float4*)&outp[base + 256 + (lane << 2)] = o1;
  if (bfout != nullptr) {
    const int n = tok >> 10, ll = tok & 1023;
    const size_t bb2 = ((size_t)n * 1026 + ll + 1) * 512;
    ushort4 u0 = make_ushort4(f2bf(o0.x), f2bf(o0.y), f2bf(o0.z), f2bf(o0.w));
    ushort4 u1 = make_ushort4(f2bf(o1.x), f2bf(o1.y), f2bf(o1.z), f2bf(o1.w));
    *(ushort4*)&bfout[bb2 + (lane << 2)] = u0;
    *(ushort4*)&bfout[bb2 + 256 + (lane << 2)] = u1;
  }
}

// ---------------------------------------------------------------------------
extern "C" void kernel_launch(void* const* d_in, const int* in_sizes, int n_in,
                              void* d_out, int out_size, void* d_ws, size_t ws_size,
                              hipStream_t stream)
{
  (void)in_sizes; (void)n_in; (void)out_size; (void)ws_size;
  const float* x      = (const float*)d_in[0];
  const float* Wq     = (const float*)d_in[1];
  const float* Wk     = (const float*)d_in[2];
  const float* Wv     = (const float*)d_in[3];
  const float* Wo     = (const float*)d_in[4];
  const float* bo     = (const float*)d_in[5];
  const float* th_pre = (const float*)d_in[6];
  const float* th_post= (const float*)d_in[7];
  const float* p_keys = (const float*)d_in[8];
  const float* p_vals = (const float*)d_in[9];
  const float* c1w    = (const float*)d_in[10];
  const float* c1b    = (const float*)d_in[11];
  const float* c2w    = (const float*)d_in[12];
  const float* c2b    = (const float*)d_in[13];
  const float* ln1g   = (const float*)d_in[14];
  const float* ln1b   = (const float*)d_in[15];
  const float* ln2g   = (const float*)d_in[16];
  const float* ln2b   = (const float*)d_in[17];

  float* ws  = (float*)d_ws;
  float* out = (float*)d_out;

  ushort_t* Qb   = (ushort_t*)(ws + O_QB);
  ushort_t* Kb   = (ushort_t*)(ws + O_KB);
  ushort_t* Vb   = (ushort_t*)(ws + O_VB);
  ushort_t* Kf   = (ushort_t*)(ws + O_KF);
  ushort_t* Vf   = (ushort_t*)(ws + O_VF);
  ushort_t* aob  = (ushort_t*)(ws + O_AOB);
  float*    abf  = ws + O_AF;
  float*    fbf  = abf;
  ushort_t* x1b  = (ushort_t*)(ws + O_X1B);
  ushort_t* hpad = (ushort_t*)(ws + O_HPAD);
  ushort_t* hraw = (ushort_t*)ws;
  ushort_t* w1p  = (ushort_t*)(ws + O_W1);
  ushort_t* w2p  = (ushort_t*)(ws + O_W2);
  ushort_t* wop  = (ushort_t*)(ws + O_WO);

  pack_bf16_kernel<<<4096, 256, 0, stream>>>(c1w, w1p, 1536, 3, 9);
  pack_bf16_kernel<<<512,  256, 0, stream>>>(c2w, w2p, 6144, 3, 11);
  pack_bf16_kernel<<<512,  256, 0, stream>>>(Wo,  wop, 512,  1, 9);

  qkv_mfma<<<dim3(128, 3), 256, 0, stream>>>(x, Wq, Wk, Wv, Qb, Kb, Vb);
  persist_kernel<<<256, 256, 0, stream>>>(p_keys, p_vals, Kb, Vb);
  kfrag_kernel<<<dim3(65, 8), 256, 0, stream>>>(Kb, Kf);
  vfrag_kernel<<<dim3(34, 8), 256, 0, stream>>>(Vb, Vf);

  attn_v5<<<512, 256, 0, stream>>>(Qb, Kf, Vf, th_pre, th_post, aob);

  // Wo: M=8192 N=512 K=512, +bias +residual(x) -> abf fp32
  mfma_gemm<2><<<dim3(64, 4), 256, 0, stream>>>(
      aob, wop, 512, 1024 * 512, 512, 512, bo, x, abf, nullptr);

  ln_kernel<<<2048, 256, 0, stream>>>(abf, nullptr, ln1g, ln1b, out, x1b);
  zero_pads_kernel<<<16, 256, 0, stream>>>(x1b, hpad);

  // conv1: M=8192 N=4096 K=1536 -> hraw bf16
  mfma_gemm<0><<<dim3(64, 32), 256, 0, stream>>>(
      x1b, w1p, 1536, 1026 * 512, 512, 4096, nullptr, nullptr, nullptr, hraw);

  swiglu_kernel<<<8192, 256, 0, stream>>>(hraw, c1b, hpad);

  // conv2: M=8192 N=512 K=6144, +bias -> fbf fp32
  mfma_gemm<1><<<dim3(64, 4), 256, 0, stream>>>(
      hpad, w2p, 6144, 1026 * 2048, 2048, 512, c2b, nullptr, fbf, nullptr);

  ln_kernel<<<2048, 256, 0, stream>>>(fbf, out, ln2g, ln2b, out, nullptr);
}